// Round 1
// baseline (209.438 us; speedup 1.0000x reference)
//
#include <hip/hip_runtime.h>
#include <hip/hip_bf16.h>

#define BS 4
#define NSEQ 2048
#define C_ 8
#define D_ 128
#define E_ 256
#define TWO_E 512
#define CHUNK 64
#define NCH (NSEQ / CHUNK) /* 32 */

typedef __attribute__((ext_vector_type(8))) short short8;
typedef __attribute__((ext_vector_type(4))) float floatx4;

__device__ __forceinline__ unsigned short f2bf(float f) {
    unsigned int u = __float_as_uint(f);
    return (unsigned short)((u + 0x7FFFu + ((u >> 16) & 1u)) >> 16);
}

__device__ __forceinline__ float sigmoidf_(float v) {
    return 1.0f / (1.0f + __expf(-v));
}

// wT_in[c][e2][d] = bf16(w_in[c][d][e2]);  w_in: [C,D,2E]
__global__ __launch_bounds__(256) void k_transpose_win(const float* __restrict__ w,
                                                       unsigned short* __restrict__ wt) {
    __shared__ float tile[32][33];
    const int c = blockIdx.z;
    const int d0 = blockIdx.y * 32;
    const int e0 = blockIdx.x * 32;
    const int tx = threadIdx.x, ty = threadIdx.y;
    #pragma unroll
    for (int k = 0; k < 4; k++)
        tile[ty + k * 8][tx] = w[((size_t)(c * D_ + d0 + ty + k * 8)) * TWO_E + e0 + tx];
    __syncthreads();
    #pragma unroll
    for (int k = 0; k < 4; k++)
        wt[((size_t)(c * TWO_E + e0 + ty + k * 8)) * D_ + d0 + tx] = f2bf(tile[tx][ty + k * 8]);
}

// wT_out[c][d][e] = bf16(w_out[c][e][d]);  w_out: [C,E,D]
__global__ __launch_bounds__(256) void k_transpose_wout(const float* __restrict__ w,
                                                        unsigned short* __restrict__ wt) {
    __shared__ float tile[32][33];
    const int c = blockIdx.z;
    const int e0 = blockIdx.y * 32;
    const int d0 = blockIdx.x * 32;
    const int tx = threadIdx.x, ty = threadIdx.y;
    #pragma unroll
    for (int k = 0; k < 4; k++)
        tile[ty + k * 8][tx] = w[((size_t)(c * E_ + e0 + ty + k * 8)) * D_ + d0 + tx];
    __syncthreads();
    #pragma unroll
    for (int k = 0; k < 4; k++)
        wt[((size_t)(c * D_ + d0 + ty + k * 8)) * E_ + e0 + tx] = f2bf(tile[tx][ty + k * 8]);
}

// K1: LayerNorm + GEMM-in + activations + per-chunk scan aggregates.
// ab_buf layout: [b][c][n][2e + {0:a,1:b}] fp32 (interleaved pairs).
__global__ __launch_bounds__(256) void k1_ln_gemm_in(
    const float* __restrict__ x, const float* __restrict__ gamma, const float* __restrict__ beta,
    const unsigned short* __restrict__ wt_in, const float* __restrict__ b_in,
    float* __restrict__ ab_buf, float* __restrict__ aggA, float* __restrict__ aggB)
{
    constexpr int LDA = 136;  // 128 + 8 bf16: lane-stride 272B -> 2-way bank alias (free)
    __shared__ unsigned short xn[CHUNK * LDA];

    const int gid = blockIdx.x;
    const int j = gid & (NCH - 1);
    const int c = (gid >> 5) & (C_ - 1);
    const int b = gid >> 8;
    const int n0 = j * CHUNK;
    const int tid = threadIdx.x;

    // ---- LayerNorm (4 threads per row, fp32) ----
    {
        const int r = tid >> 2;
        const int p = tid & 3;
        const float* xrow = x + ((size_t)((b * NSEQ + n0 + r) * C_) + c) * D_;
        float4 xv[8];
        float s = 0.f, ss = 0.f;
        #pragma unroll
        for (int i = 0; i < 8; i++) {
            xv[i] = ((const float4*)xrow)[p + 4 * i];
            s += xv[i].x + xv[i].y + xv[i].z + xv[i].w;
            ss += xv[i].x * xv[i].x + xv[i].y * xv[i].y + xv[i].z * xv[i].z + xv[i].w * xv[i].w;
        }
        s += __shfl_xor(s, 1);  s += __shfl_xor(s, 2);
        ss += __shfl_xor(ss, 1); ss += __shfl_xor(ss, 2);
        const float mu = s * (1.0f / D_);
        const float rsig = rsqrtf(fmaxf(ss * (1.0f / D_) - mu * mu, 0.f) + 1e-5f);
        #pragma unroll
        for (int i = 0; i < 8; i++) {
            const int f = p + 4 * i;
            const float4 g  = ((const float4*)(gamma + c * D_))[f];
            const float4 bt = ((const float4*)(beta + c * D_))[f];
            ushort4 o;
            o.x = f2bf((xv[i].x - mu) * rsig * g.x + bt.x);
            o.y = f2bf((xv[i].y - mu) * rsig * g.y + bt.y);
            o.z = f2bf((xv[i].z - mu) * rsig * g.z + bt.z);
            o.w = f2bf((xv[i].w - mu) * rsig * g.w + bt.w);
            *(ushort4*)&xn[r * LDA + 4 * f] = o;
        }
    }
    __syncthreads();

    // ---- GEMM [64x128] @ [128x512] via mfma_f32_16x16x32_bf16 ----
    const int wave = tid >> 6;
    const int lane = tid & 63;
    const int lrow = lane & 15;
    const int quad = lane >> 4;

    short8 afr[4][4];  // A frag cache: [mtile][kstep]
    #pragma unroll
    for (int m = 0; m < 4; m++) {
        #pragma unroll
        for (int k = 0; k < 4; k++)
            afr[m][k] = *(const short8*)&xn[(m * 16 + lrow) * LDA + k * 32 + quad * 8];
    }

    const unsigned short* wbase = wt_in + (size_t)c * TWO_E * D_;
    float* abrow0 = ab_buf + ((size_t)(b * C_ + c) * NSEQ + n0) * TWO_E;

    #pragma unroll
    for (int nt = 0; nt < 8; nt++) {
        const int e2 = wave * 128 + nt * 16 + lrow;  // waves 0,1 -> a cols; 2,3 -> b cols
        short8 bfr[4];
        #pragma unroll
        for (int k = 0; k < 4; k++)
            bfr[k] = *(const short8*)&wbase[(size_t)e2 * D_ + k * 32 + quad * 8];
        floatx4 acc[4];
        #pragma unroll
        for (int m = 0; m < 4; m++) acc[m] = (floatx4){0.f, 0.f, 0.f, 0.f};
        #pragma unroll
        for (int m = 0; m < 4; m++) {
            #pragma unroll
            for (int k = 0; k < 4; k++)
                acc[m] = __builtin_amdgcn_mfma_f32_16x16x32_bf16(afr[m][k], bfr[k], acc[m], 0, 0, 0);
        }
        const float bias = b_in[c * TWO_E + e2];
        const int col = (e2 < E_) ? (2 * e2) : (2 * (e2 - E_) + 1);
        #pragma unroll
        for (int m = 0; m < 4; m++) {
            #pragma unroll
            for (int rr = 0; rr < 4; rr++) {
                const int row = m * 16 + quad * 4 + rr;  // D-layout: row=quad*4+rr, col=lrow
                const float v = acc[m][rr] + bias;
                const float sg = sigmoidf_(v);
                abrow0[(size_t)row * TWO_E + col] = (e2 < E_) ? sg : (v * sg);
            }
        }
    }

    __threadfence_block();
    __syncthreads();

    // ---- chunk aggregate: compose (a,b) over the 64 rows (reads own L2-hot tile) ----
    {
        const int e = tid;  // 0..255
        float A = 1.f, Bv = 0.f;
        const float* pr = abrow0 + 2 * e;
        #pragma unroll 8
        for (int i = 0; i < CHUNK; i++) {
            const float2 v = *(const float2*)&pr[(size_t)i * TWO_E];
            A = v.x * A;
            Bv = v.x * Bv + v.y;
        }
        const size_t o = ((size_t)(b * C_ + c) * NCH + j) * E_ + e;
        aggA[o] = A;
        aggB[o] = Bv;
    }
}

// K2: scan over chunk aggregates; seeds with h_prev; emits h_in per chunk and h[:, -1].
__global__ __launch_bounds__(256) void k2_scan_chunks(
    const float* __restrict__ h_prev, const float* __restrict__ aggA, const float* __restrict__ aggB,
    float* __restrict__ hin, float* __restrict__ h_last)
{
    const int bc = blockIdx.x;      // b*C + c  (32 blocks)
    const int e = threadIdx.x;      // 0..255
    float h = h_prev[(size_t)bc * E_ + e];
    const size_t base = (size_t)bc * NCH * E_ + e;
    #pragma unroll
    for (int jj = 0; jj < NCH; jj++) {
        hin[base + (size_t)jj * E_] = h;
        h = aggA[base + (size_t)jj * E_] * h + aggB[base + (size_t)jj * E_];
    }
    h_last[(size_t)bc * E_ + e] = h;
}

// K3: per-chunk scan replay + GEMM-out + bias + residual.
__global__ __launch_bounds__(256) void k3_scan_gemm_out(
    const float* __restrict__ ab_buf, const float* __restrict__ hin,
    const unsigned short* __restrict__ wt_out, const float* __restrict__ b_out,
    const float* __restrict__ x, float* __restrict__ out)
{
    constexpr int LDH = 264;  // 256 + 8 bf16
    __shared__ unsigned short hs[CHUNK * LDH];

    const int gid = blockIdx.x;
    const int j = gid & (NCH - 1);
    const int c = (gid >> 5) & (C_ - 1);
    const int b = gid >> 8;
    const int n0 = j * CHUNK;
    const int tid = threadIdx.x;

    // ---- local scan from h_in ----
    {
        const int e = tid;
        float h = hin[((size_t)(b * C_ + c) * NCH + j) * E_ + e];
        const float* pr = ab_buf + ((size_t)(b * C_ + c) * NSEQ + n0) * TWO_E + 2 * e;
        #pragma unroll
        for (int i = 0; i < CHUNK; i++) {
            const float2 v = *(const float2*)&pr[(size_t)i * TWO_E];
            h = v.x * h + v.y;
            hs[i * LDH + e] = f2bf(h);
        }
    }
    __syncthreads();

    // ---- GEMM [64x256] @ [256x128] + b_out + x ----
    const int wave = tid >> 6;
    const int lane = tid & 63;
    const int lrow = lane & 15;
    const int quad = lane >> 4;
    const int m0 = wave * 16;

    short8 afr[8];
    #pragma unroll
    for (int k = 0; k < 8; k++)
        afr[k] = *(const short8*)&hs[(m0 + lrow) * LDH + k * 32 + quad * 8];

    const unsigned short* wbase = wt_out + (size_t)c * D_ * E_;

    #pragma unroll
    for (int nt = 0; nt < 8; nt++) {
        const int d = nt * 16 + lrow;
        short8 bfr[8];
        #pragma unroll
        for (int k = 0; k < 8; k++)
            bfr[k] = *(const short8*)&wbase[(size_t)d * E_ + k * 32 + quad * 8];
        floatx4 acc = (floatx4){0.f, 0.f, 0.f, 0.f};
        #pragma unroll
        for (int k = 0; k < 8; k++)
            acc = __builtin_amdgcn_mfma_f32_16x16x32_bf16(afr[k], bfr[k], acc, 0, 0, 0);
        const float bias = b_out[c * D_ + d];
        #pragma unroll
        for (int rr = 0; rr < 4; rr++) {
            const int row = m0 + quad * 4 + rr;
            const size_t xi = ((size_t)((b * NSEQ + n0 + row) * C_) + c) * D_ + d;
            out[xi] = acc[rr] + bias + x[xi];
        }
    }
}

extern "C" void kernel_launch(void* const* d_in, const int* in_sizes, int n_in,
                              void* d_out, int out_size, void* d_ws, size_t ws_size,
                              hipStream_t stream) {
    (void)in_sizes; (void)n_in; (void)out_size; (void)ws_size;
    const float* x      = (const float*)d_in[0];
    const float* h_prev = (const float*)d_in[1];
    const float* gamma  = (const float*)d_in[2];
    const float* beta   = (const float*)d_in[3];
    const float* w_in   = (const float*)d_in[4];
    const float* b_in   = (const float*)d_in[5];
    const float* w_out  = (const float*)d_in[6];
    const float* b_out  = (const float*)d_in[7];

    float* out    = (float*)d_out;                           // [BS,N,C,D]
    float* h_last = out + (size_t)BS * NSEQ * C_ * D_;       // [BS,C,E]

    float* ws = (float*)d_ws;
    size_t off = 0;
    float* ab_buf = ws + off; off += (size_t)BS * C_ * NSEQ * TWO_E;   // 33,554,432 f
    float* aggA   = ws + off; off += (size_t)BS * C_ * NCH * E_;       // 262,144 f
    float* aggB   = ws + off; off += (size_t)BS * C_ * NCH * E_;
    float* hin    = ws + off; off += (size_t)BS * C_ * NCH * E_;
    unsigned short* wt_in  = (unsigned short*)(ws + off); off += (size_t)C_ * TWO_E * D_ / 2;
    unsigned short* wt_out = (unsigned short*)(ws + off); off += (size_t)C_ * D_ * E_ / 2;

    k_transpose_win <<<dim3(16, 4, 8), dim3(32, 8), 0, stream>>>(w_in, wt_in);
    k_transpose_wout<<<dim3(4, 8, 8),  dim3(32, 8), 0, stream>>>(w_out, wt_out);
    k1_ln_gemm_in   <<<BS * C_ * NCH, 256, 0, stream>>>(x, gamma, beta, wt_in, b_in,
                                                        ab_buf, aggA, aggB);
    k2_scan_chunks  <<<BS * C_, 256, 0, stream>>>(h_prev, aggA, aggB, hin, h_last);
    k3_scan_gemm_out<<<BS * C_ * NCH, 256, 0, stream>>>(ab_buf, hin, wt_out, b_out, x, out);
}

// Round 4
// 201.948 us; speedup vs baseline: 1.0371x; 1.0371x over previous
//
#include <hip/hip_runtime.h>
#include <hip/hip_bf16.h>

#define BS 4
#define NSEQ 2048
#define C_ 8
#define D_ 128
#define E_ 256
#define TWO_E 512
#define CHUNK 64
#define NCH (NSEQ / CHUNK) /* 32 */

typedef __attribute__((ext_vector_type(8))) short short8;
typedef __attribute__((ext_vector_type(4))) float floatx4;

__device__ __forceinline__ unsigned short f2bf(float f) {
    unsigned int u = __float_as_uint(f);
    return (unsigned short)((u + 0x7FFFu + ((u >> 16) & 1u)) >> 16);
}
__device__ __forceinline__ float sigmoidf_(float v) {
    return 1.0f / (1.0f + __expf(-v));
}

// LayerNorm of a 64-row chunk into LDS bf16 tile (stride 136 shorts).
__device__ __forceinline__ void layernorm_tile(
    const float* __restrict__ x, const float* __restrict__ gamma, const float* __restrict__ beta,
    int b, int c, int n0, int tid, unsigned short* __restrict__ xn)
{
    const int r = tid >> 2;
    const int p = tid & 3;
    const float* xrow = x + ((size_t)((b * NSEQ + n0 + r) * C_) + c) * D_;
    float4 xv[8];
    float s = 0.f, ss = 0.f;
    #pragma unroll
    for (int i = 0; i < 8; i++) {
        xv[i] = ((const float4*)xrow)[p + 4 * i];
        s += xv[i].x + xv[i].y + xv[i].z + xv[i].w;
        ss += xv[i].x * xv[i].x + xv[i].y * xv[i].y + xv[i].z * xv[i].z + xv[i].w * xv[i].w;
    }
    s += __shfl_xor(s, 1);  s += __shfl_xor(s, 2);
    ss += __shfl_xor(ss, 1); ss += __shfl_xor(ss, 2);
    const float mu = s * (1.0f / D_);
    const float rsig = rsqrtf(fmaxf(ss * (1.0f / D_) - mu * mu, 0.f) + 1e-5f);
    #pragma unroll
    for (int i = 0; i < 8; i++) {
        const int f = p + 4 * i;
        const float4 g  = ((const float4*)(gamma + c * D_))[f];
        const float4 bt = ((const float4*)(beta + c * D_))[f];
        ushort4 o;
        o.x = f2bf((xv[i].x - mu) * rsig * g.x + bt.x);
        o.y = f2bf((xv[i].y - mu) * rsig * g.y + bt.y);
        o.z = f2bf((xv[i].z - mu) * rsig * g.z + bt.z);
        o.w = f2bf((xv[i].w - mu) * rsig * g.w + bt.w);
        *(ushort4*)&xn[r * 136 + 4 * f] = o;
    }
}

// wT_in[c][e2][d] = bf16(w_in[c][d][e2]);  w_in: [C,D,2E]
__global__ __launch_bounds__(256) void k_transpose_win(const float* __restrict__ w,
                                                       unsigned short* __restrict__ wt) {
    __shared__ float tile[32][33];
    const int c = blockIdx.z;
    const int d0 = blockIdx.y * 32;
    const int e0 = blockIdx.x * 32;
    const int tx = threadIdx.x, ty = threadIdx.y;
    #pragma unroll
    for (int k = 0; k < 4; k++)
        tile[ty + k * 8][tx] = w[((size_t)(c * D_ + d0 + ty + k * 8)) * TWO_E + e0 + tx];
    __syncthreads();
    #pragma unroll
    for (int k = 0; k < 4; k++)
        wt[((size_t)(c * TWO_E + e0 + ty + k * 8)) * D_ + d0 + tx] = f2bf(tile[tx][ty + k * 8]);
}

// wT_out[c][d][e] = bf16(w_out[c][e][d]);  w_out: [C,E,D]
__global__ __launch_bounds__(256) void k_transpose_wout(const float* __restrict__ w,
                                                        unsigned short* __restrict__ wt) {
    __shared__ float tile[32][33];
    const int c = blockIdx.z;
    const int e0 = blockIdx.y * 32;
    const int d0 = blockIdx.x * 32;
    const int tx = threadIdx.x, ty = threadIdx.y;
    #pragma unroll
    for (int k = 0; k < 4; k++)
        tile[ty + k * 8][tx] = w[((size_t)(c * E_ + e0 + ty + k * 8)) * D_ + d0 + tx];
    __syncthreads();
    #pragma unroll
    for (int k = 0; k < 4; k++)
        wt[((size_t)(c * D_ + d0 + ty + k * 8)) * E_ + e0 + tx] = f2bf(tile[tx][ty + k * 8]);
}

// K1: LN + GEMM-in + activations + chunk transform composed IN REGISTERS
// (in-lane 4-step compose, cross-quad butterfly, m-block fold; all fp32).
// MFMA chain order (m outer, k inner) MUST match K3 so activations are
// bitwise identical -> hin is exactly consistent with K3's scan.
__global__ __launch_bounds__(256) void k1_agg(
    const float* __restrict__ x, const float* __restrict__ gamma, const float* __restrict__ beta,
    const unsigned short* __restrict__ wt_in, const float* __restrict__ b_in,
    float* __restrict__ aggA, float* __restrict__ aggB)
{
    constexpr int LDA = 136;
    __shared__ unsigned short xn[CHUNK * LDA];

    const int gid = blockIdx.x;
    const int j = gid & (NCH - 1);
    const int c = (gid >> 5) & (C_ - 1);
    const int b = gid >> 8;
    const int n0 = j * CHUNK;
    const int tid = threadIdx.x;

    layernorm_tile(x, gamma, beta, b, c, n0, tid, xn);
    __syncthreads();

    const int wave = tid >> 6;
    const int lane = tid & 63;
    const int lrow = lane & 15;
    const int quad = lane >> 4;

    short8 afr[4][4];
    #pragma unroll
    for (int m = 0; m < 4; m++)
        #pragma unroll
        for (int k = 0; k < 4; k++)
            afr[m][k] = *(const short8*)&xn[(m * 16 + lrow) * LDA + k * 32 + quad * 8];

    const unsigned short* wbi = wt_in + (size_t)c * TWO_E * D_;
    const size_t aggbase = ((size_t)(b * C_ + c) * NCH + j) * E_;

    #pragma unroll
    for (int p = 0; p < 4; p++) {
        const int ea = wave * 64 + p * 16 + lrow;
        const int eb = E_ + ea;
        short8 bfa[4], bfb[4];
        #pragma unroll
        for (int k = 0; k < 4; k++) {
            bfa[k] = *(const short8*)&wbi[(size_t)ea * D_ + k * 32 + quad * 8];
            bfb[k] = *(const short8*)&wbi[(size_t)eb * D_ + k * 32 + quad * 8];
        }
        floatx4 accA[4], accB[4];
        #pragma unroll
        for (int m = 0; m < 4; m++) { accA[m] = (floatx4){0,0,0,0}; accB[m] = (floatx4){0,0,0,0}; }
        #pragma unroll
        for (int m = 0; m < 4; m++)
            #pragma unroll
            for (int k = 0; k < 4; k++) {
                accA[m] = __builtin_amdgcn_mfma_f32_16x16x32_bf16(afr[m][k], bfa[k], accA[m], 0, 0, 0);
                accB[m] = __builtin_amdgcn_mfma_f32_16x16x32_bf16(afr[m][k], bfb[k], accB[m], 0, 0, 0);
            }
        const float biasa = b_in[c * TWO_E + ea];
        const float biasb = b_in[c * TWO_E + eb];

        float Ac = 1.f, Bc = 0.f;
        #pragma unroll
        for (int m = 0; m < 4; m++) {
            float A = 1.f, B = 0.f;
            #pragma unroll
            for (int rr = 0; rr < 4; rr++) {
                const float av = sigmoidf_(accA[m][rr] + biasa);
                const float rv = accB[m][rr] + biasb;
                const float bv = rv * sigmoidf_(rv);
                A = av * A;
                B = av * B + bv;
            }
            #pragma unroll
            for (int s = 16; s <= 32; s <<= 1) {
                const float Ap = __shfl_xor(A, s);
                const float Bp = __shfl_xor(B, s);
                B = (lane & s) ? (A * Bp + B) : (Ap * B + Bp);
                A = A * Ap;
            }
            Bc = A * Bc + B;
            Ac = A * Ac;
        }
        if (quad == 0) {
            aggA[aggbase + ea] = Ac;
            aggB[aggbase + ea] = Bc;
        }
    }
}

// K2: sequential scan over the 32 chunk aggregates; seeds with h_prev.
__global__ __launch_bounds__(256) void k2_scan_chunks(
    const float* __restrict__ h_prev, const float* __restrict__ aggA, const float* __restrict__ aggB,
    float* __restrict__ hin, float* __restrict__ h_last)
{
    const int bc = blockIdx.x;
    const int e = threadIdx.x;
    float h = h_prev[(size_t)bc * E_ + e];
    const size_t base = (size_t)bc * NCH * E_ + e;
    #pragma unroll
    for (int jj = 0; jj < NCH; jj++) {
        hin[base + (size_t)jj * E_] = h;
        h = aggA[base + (size_t)jj * E_] * h + aggB[base + (size_t)jj * E_];
    }
    h_last[(size_t)bc * E_ + e] = h;
}

// K3: LN + GEMM-in (recomputed, bitwise == K1) + fp32 scan + K-split GEMM-out
//     + bias + residual. Four quarter-passes of 64 E-columns so (a,b) stay
//     fp32 in LDS: xn 17408B + abq 33280B + hq 8704B = 59392B (2 blocks/CU).
__global__ __launch_bounds__(256) void k3_fused(
    const float* __restrict__ x, const float* __restrict__ gamma, const float* __restrict__ beta,
    const unsigned short* __restrict__ wt_in, const float* __restrict__ b_in,
    const float* __restrict__ hin,
    const unsigned short* __restrict__ wt_out, const float* __restrict__ b_out,
    float* __restrict__ out)
{
    constexpr int LDX = 136;   // xn stride (shorts), persistent all quarters
    constexpr int LDAB = 65;   // abq stride (float2)
    constexpr int LDQ = 68;    // hq stride (shorts)
    __shared__ unsigned short xn[CHUNK * LDX];
    __shared__ float2 abq[CHUNK * LDAB];
    __shared__ unsigned short hq[CHUNK * LDQ];

    const int gid = blockIdx.x;
    const int j = gid & (NCH - 1);
    const int c = (gid >> 5) & (C_ - 1);
    const int b = gid >> 8;
    const int n0 = j * CHUNK;
    const int tid = threadIdx.x;

    layernorm_tile(x, gamma, beta, b, c, n0, tid, xn);
    __syncthreads();

    const int wave = tid >> 6;
    const int lane = tid & 63;
    const int lrow = lane & 15;
    const int quad = lane >> 4;
    const int m0 = wave * 16;

    const unsigned short* wbi = wt_in + (size_t)c * TWO_E * D_;
    const unsigned short* wbo = wt_out + (size_t)c * D_ * E_;
    const size_t hinbase = ((size_t)(b * C_ + c) * NCH + j) * E_;

    floatx4 acco[8];
    #pragma unroll
    for (int nt = 0; nt < 8; nt++) acco[nt] = (floatx4){0, 0, 0, 0};

    #pragma unroll
    for (int q = 0; q < 4; q++) {
        // ---- GEMM-in: this wave's 16 matched a/b column pairs of quarter q ----
        {
            const int eq = wave * 16 + lrow;          // column within quarter [0,64)
            const int ea = q * 64 + eq;
            const int eb = E_ + ea;
            short8 bfa[4], bfb[4];
            #pragma unroll
            for (int k = 0; k < 4; k++) {
                bfa[k] = *(const short8*)&wbi[(size_t)ea * D_ + k * 32 + quad * 8];
                bfb[k] = *(const short8*)&wbi[(size_t)eb * D_ + k * 32 + quad * 8];
            }
            floatx4 accA[4], accB[4];
            #pragma unroll
            for (int m = 0; m < 4; m++) { accA[m] = (floatx4){0,0,0,0}; accB[m] = (floatx4){0,0,0,0}; }
            #pragma unroll
            for (int m = 0; m < 4; m++) {
                short8 afr[4];
                #pragma unroll
                for (int k = 0; k < 4; k++)
                    afr[k] = *(const short8*)&xn[(m * 16 + lrow) * LDX + k * 32 + quad * 8];
                #pragma unroll
                for (int k = 0; k < 4; k++) {
                    accA[m] = __builtin_amdgcn_mfma_f32_16x16x32_bf16(afr[k], bfa[k], accA[m], 0, 0, 0);
                    accB[m] = __builtin_amdgcn_mfma_f32_16x16x32_bf16(afr[k], bfb[k], accB[m], 0, 0, 0);
                }
            }
            const float biasa = b_in[c * TWO_E + ea];
            const float biasb = b_in[c * TWO_E + eb];
            #pragma unroll
            for (int m = 0; m < 4; m++)
                #pragma unroll
                for (int rr = 0; rr < 4; rr++) {
                    const int row = m * 16 + quad * 4 + rr;
                    const float av = sigmoidf_(accA[m][rr] + biasa);
                    const float rv = accB[m][rr] + biasb;
                    const float bv = rv * sigmoidf_(rv);
                    abq[row * LDAB + eq] = make_float2(av, bv);
                }
        }
        __syncthreads();  // abq ready; prior quarter's abq reads done (pre-sync)

        // ---- fp32 scan: 64 threads, one column each ----
        if (tid < 64) {
            float h = hin[hinbase + q * 64 + tid];
            #pragma unroll
            for (int i = 0; i < CHUNK; i++) {
                const float2 v = abq[i * LDAB + tid];
                h = v.x * h + v.y;
                hq[i * LDQ + tid] = f2bf(h);
            }
        }
        __syncthreads();  // hq ready; prior quarter's hq reads done (pre-sync)

        // ---- GEMM-out partial accumulation over K-slice [64q, 64q+64) ----
        short8 af2[2];
        #pragma unroll
        for (int k = 0; k < 2; k++)
            af2[k] = *(const short8*)&hq[(m0 + lrow) * LDQ + k * 32 + quad * 8];
        #pragma unroll
        for (int nt = 0; nt < 8; nt++) {
            const int d = nt * 16 + lrow;
            short8 bf2_[2];
            #pragma unroll
            for (int k = 0; k < 2; k++)
                bf2_[k] = *(const short8*)&wbo[(size_t)d * E_ + q * 64 + k * 32 + quad * 8];
            #pragma unroll
            for (int k = 0; k < 2; k++)
                acco[nt] = __builtin_amdgcn_mfma_f32_16x16x32_bf16(af2[k], bf2_[k], acco[nt], 0, 0, 0);
        }
        // next quarter's "abq ready" sync orders abq/hq overwrites after these reads
    }

    // ---- epilogue: bias + residual ----
    #pragma unroll
    for (int nt = 0; nt < 8; nt++) {
        const int d = nt * 16 + lrow;
        const float bias = b_out[c * D_ + d];
        #pragma unroll
        for (int rr = 0; rr < 4; rr++) {
            const int row = m0 + quad * 4 + rr;
            const size_t xi = ((size_t)((b * NSEQ + n0 + row) * C_) + c) * D_ + d;
            out[xi] = acco[nt][rr] + bias + x[xi];
        }
    }
}

extern "C" void kernel_launch(void* const* d_in, const int* in_sizes, int n_in,
                              void* d_out, int out_size, void* d_ws, size_t ws_size,
                              hipStream_t stream) {
    (void)in_sizes; (void)n_in; (void)out_size; (void)ws_size;
    const float* x      = (const float*)d_in[0];
    const float* h_prev = (const float*)d_in[1];
    const float* gamma  = (const float*)d_in[2];
    const float* beta   = (const float*)d_in[3];
    const float* w_in   = (const float*)d_in[4];
    const float* b_in   = (const float*)d_in[5];
    const float* w_out  = (const float*)d_in[6];
    const float* b_out  = (const float*)d_in[7];

    float* out    = (float*)d_out;                        // [BS,N,C,D]
    float* h_last = out + (size_t)BS * NSEQ * C_ * D_;    // [BS,C,E]

    float* ws = (float*)d_ws;
    size_t off = 0;
    float* aggA = ws + off; off += (size_t)BS * C_ * NCH * E_;   // 262,144 f
    float* aggB = ws + off; off += (size_t)BS * C_ * NCH * E_;
    float* hin  = ws + off; off += (size_t)BS * C_ * NCH * E_;
    unsigned short* wt_in  = (unsigned short*)(ws + off); off += (size_t)C_ * TWO_E * D_ / 2;
    unsigned short* wt_out = (unsigned short*)(ws + off); off += (size_t)C_ * D_ * E_ / 2;

    k_transpose_win <<<dim3(16, 4, 8), dim3(32, 8), 0, stream>>>(w_in, wt_in);
    k_transpose_wout<<<dim3(4, 8, 8),  dim3(32, 8), 0, stream>>>(w_out, wt_out);
    k1_agg          <<<BS * C_ * NCH, 256, 0, stream>>>(x, gamma, beta, wt_in, b_in, aggA, aggB);
    k2_scan_chunks  <<<BS * C_, 256, 0, stream>>>(h_prev, aggA, aggB, hin, h_last);
    k3_fused        <<<BS * C_ * NCH, 256, 0, stream>>>(x, gamma, beta, wt_in, b_in,
                                                        hin, wt_out, b_out, out);
}